// Round 5
// baseline (141.095 us; speedup 1.0000x reference)
//
#include <hip/hip_runtime.h>

// Sliding-window attention, window=127 (+-63), B=4 L=4096 NH=16 H=64, fp32 in/out.
// Round-5: occupancy + pipelining. R4 (54us) was latency-bound at 2 blocks/CU (80KB LDS),
// monolithic stage->barrier->compute.
//  - LDS 80KB -> 32KB: K rolling 4 slots x [32][64] f16 (16KB), V rolling [64][256B]
//    transposed (16KB), Q not staged (direct strided loads, prologue-only, hidden).
//    -> 4-5 blocks/CU instead of 2.
//  - Software pipeline: tile i+4 global loads issued at top of iteration i; cvt+ds_write
//    lands after compute between two barriers (T14 async-stage split; slot (i+4)&3 is
//    tile i's slot, whose reads completed at barrier 1).
//  - V swizzle chunk ^= ((h&15)^((h>>2)&15)): bijective per 16-lane group for BOTH the
//    f16x2 write pattern (h multiples of 4) and the b128 read pattern (h consecutive).
//  - amdgpu_waves_per_eu(4,4): 128-VGPR budget; avoids R3's 64-VGPR spill pathology.

typedef _Float16 f16;
typedef _Float16 f16x2  __attribute__((ext_vector_type(2)));
typedef _Float16 f16x4  __attribute__((ext_vector_type(4)));
typedef _Float16 f16x8  __attribute__((ext_vector_type(8)));
typedef float    f32x16 __attribute__((ext_vector_type(16)));
typedef int      int4v  __attribute__((ext_vector_type(4)));

constexpr int NB = 4, L = 4096, NH = 16, H = 64;
constexpr int CQ = 128, NC = L / CQ, KW = 256, WR = 63;
constexpr int RS = NH * H;   // seq-row stride in floats

constexpr int K_OFF = 0;       // 4 slots x [32][64] f16, swizzled, 4KB/slot
constexpr int V_OFF = 16384;   // [64][256B] transposed, swizzled
constexpr int LDS_BYTES = 32768;

#define DEV static __device__ __forceinline__

DEV int iclamp(int x, int lo, int hi) { return x < lo ? lo : (x > hi ? hi : x); }

DEV float fexp2(float x) {
#if __has_builtin(__builtin_amdgcn_exp2f)
    return __builtin_amdgcn_exp2f(x);
#else
    return exp2f(x);
#endif
}

DEV int packh2(float a, float b) {
    f16x2 p; p.x = (f16)a; p.y = (f16)b;   // RNE casts
    return __builtin_bit_cast(int, p);
}

// K slot addressing: slot s, local key row r (0..31), byte col (0..127)
DEV int kaddr(int slot, int r, int colb) {
    return K_OFF + slot * 4096 + r * 128 + (colb ^ ((r & 7) << 4));
}

// V addressing: row h (0..63), byte col (0..255; slot s = cols s*64..s*64+63)
DEV int vaddr(int h, int colb) {
    int swz = ((h & 15) ^ ((h >> 2) & 15)) << 4;
    return V_OFF + h * 256 + (colb ^ swz);
}

// float index of (row q, col h) in swizzled O_lds
DEV int oaddr(int row, int col) {
    return (row * 64 + col) ^ ((row & 3) << 2);
}

// After call: new_a[l<32]=a[l], new_a[l>=32]=b[l^32]; new_b[l<32]=a[l^32], new_b[l>=32]=b[l].
DEV void swap_halves(int& a, int& b, int hi) {
    int pa = __shfl_xor(a, 32, 64);
    int pb = __shfl_xor(b, 32, 64);
    int na = hi ? pb : a;
    int nb = hi ? b  : pa;
    a = na; b = nb;
}

__global__ __launch_bounds__(256) __attribute__((amdgpu_waves_per_eu(4, 4)))
void wattn_kernel(const float* __restrict__ q_, const float* __restrict__ k_,
                  const float* __restrict__ v_, float* __restrict__ o_)
{
    __shared__ alignas(16) char smem[LDS_BYTES];
    float* O_lds = (float*)smem;   // aliases K+V regions after the post-loop barrier

    // XCD-aware swizzle: 2048 blocks, 8 XCDs, 2048%8==0 -> bijective
    const int bid = (int)blockIdx.x;
    const int wid = (bid & 7) * ((NB * NH * NC) / 8) + (bid >> 3);
    const int c = wid & (NC - 1);
    const int n = (wid >> 5) & (NH - 1);
    const int b = wid >> 9;

    const int t    = (int)threadIdx.x;
    const int lane = t & 63;
    const int wq   = t >> 6;       // wave id = 32-query tile
    const int lq   = lane & 31;
    const int hi   = lane >> 5;

    const int kg0 = c * CQ - WR;                       // global seq row of window key j=0
    const size_t bn = ((size_t)b * L * NH + n) * H;    // element offset of (b,0,n,0)
    const float qs = 0.125f * 1.44269504088896f;       // h^-0.5 * log2(e)

    // staging thread->element mapping (per 32-key tile)
    const int h4  = (t & 15) << 2;       // float col 0,4,..,60
    const int rK  = t >> 4;              // K local rows {rK, rK+16}
    const int rV0 = (t >> 4) << 1;       // V local even row pair {rV0, rV0+1}

    // ---- prologue: issue Q (direct) + tiles 0..3 K/V stage ----
    const int iq = wq * 32 + lq;
    const float* qrow = q_ + bn + (size_t)(c * CQ + iq) * RS + hi * 8;
    float4 qa[8];
    #pragma unroll
    for (int tq = 0; tq < 4; ++tq) {
        qa[2 * tq]     = *(const float4*)(qrow + tq * 16);
        qa[2 * tq + 1] = *(const float4*)(qrow + tq * 16 + 4);
    }

    #pragma unroll
    for (int T = 0; T < 4; ++T) {
        // K tile T: rows rK, rK+16
        int kr0 = iclamp(kg0 + T * 32 + rK,      0, L - 1);
        int kr1 = iclamp(kg0 + T * 32 + rK + 16, 0, L - 1);
        float4 x0 = *(const float4*)(k_ + bn + (size_t)kr0 * RS + h4);
        float4 x1 = *(const float4*)(k_ + bn + (size_t)kr1 * RS + h4);
        *(f16x4*)(smem + kaddr(T, rK,      h4 << 1)) = (f16x4){(f16)x0.x, (f16)x0.y, (f16)x0.z, (f16)x0.w};
        *(f16x4*)(smem + kaddr(T, rK + 16, h4 << 1)) = (f16x4){(f16)x1.x, (f16)x1.y, (f16)x1.z, (f16)x1.w};
        // V tile T: row pair rV0, rV0+1 (transposed write)
        int vr0 = iclamp(kg0 + T * 32 + rV0,     0, L - 1);
        int vr1 = iclamp(kg0 + T * 32 + rV0 + 1, 0, L - 1);
        float4 v0 = *(const float4*)(v_ + bn + (size_t)vr0 * RS + h4);
        float4 v1 = *(const float4*)(v_ + bn + (size_t)vr1 * RS + h4);
        int vcb = T * 64 + rV0 * 2;
        *(f16x2*)(smem + vaddr(h4 + 0, vcb)) = (f16x2){(f16)v0.x, (f16)v1.x};
        *(f16x2*)(smem + vaddr(h4 + 1, vcb)) = (f16x2){(f16)v0.y, (f16)v1.y};
        *(f16x2*)(smem + vaddr(h4 + 2, vcb)) = (f16x2){(f16)v0.z, (f16)v1.z};
        *(f16x2*)(smem + vaddr(h4 + 3, vcb)) = (f16x2){(f16)v0.w, (f16)v1.w};
    }

    // Q fragments (B-operand: lane holds Q[q=lq][h = 16*tq + 8*hi + j])
    f16x8 qf[4];
    #pragma unroll
    for (int tq = 0; tq < 4; ++tq) {
        float4 a = qa[2 * tq], b2 = qa[2 * tq + 1];
        qf[tq] = (f16x8){(f16)(a.x * qs),  (f16)(a.y * qs),  (f16)(a.z * qs),  (f16)(a.w * qs),
                         (f16)(b2.x * qs), (f16)(b2.y * qs), (f16)(b2.z * qs), (f16)(b2.w * qs)};
    }

    // window mask bounds: allowed local keys j with j-iq in [0,126] and kg0+j in [0,L)
    const int jlo = (c == 0) ? WR : 0;
    const int jhi = (KW < L - kg0) ? KW : (L - kg0);
    const int lo  = (iq > jlo) ? iq : jlo;
    const int hb  = (iq + 126 < jhi - 1) ? (iq + 126) : (jhi - 1);
    const unsigned span = (unsigned)(hb - lo);

    f32x16 o0, o1;
    #pragma unroll
    for (int r = 0; r < 16; ++r) { o0[r] = 0.f; o1[r] = 0.f; }
    float dsum = 0.f;

    __syncthreads();   // tiles 0..3 staged

    #pragma unroll
    for (int i = 0; i < 5; ++i) {
        const int kt   = wq + i;
        const int slot = kt & 3;

        // ---- issue next tile's global loads (consumed after barrier 1) ----
        float4 gk0, gk1, gv0, gv1;
        if (i < 4) {
            const int T = i + 4;
            int kr0 = iclamp(kg0 + T * 32 + rK,      0, L - 1);
            int kr1 = iclamp(kg0 + T * 32 + rK + 16, 0, L - 1);
            gk0 = *(const float4*)(k_ + bn + (size_t)kr0 * RS + h4);
            gk1 = *(const float4*)(k_ + bn + (size_t)kr1 * RS + h4);
            int vr0 = iclamp(kg0 + T * 32 + rV0,     0, L - 1);
            int vr1 = iclamp(kg0 + T * 32 + rV0 + 1, 0, L - 1);
            gv0 = *(const float4*)(v_ + bn + (size_t)vr0 * RS + h4);
            gv1 = *(const float4*)(v_ + bn + (size_t)vr1 * RS + h4);
            __builtin_amdgcn_sched_barrier(0);   // pin issue here; latency hides under compute
        }

        // ---- fragments from LDS ----
        f16x8 kf[4];
        #pragma unroll
        for (int tq = 0; tq < 4; ++tq)
            kf[tq] = *(const f16x8*)(smem + kaddr(slot, lq, 32 * tq + 16 * hi));
        const int vcb = slot * 64 + hi * 16;
        f16x8 vb00 = *(const f16x8*)(smem + vaddr(lq,      vcb));
        f16x8 vb01 = *(const f16x8*)(smem + vaddr(lq,      vcb + 32));
        f16x8 vb10 = *(const f16x8*)(smem + vaddr(32 + lq, vcb));
        f16x8 vb11 = *(const f16x8*)(smem + vaddr(32 + lq, vcb + 32));

        // ---- S^T tile = K_tile(32k x 64h) . Q^T ----
        f32x16 s;
        #pragma unroll
        for (int r = 0; r < 16; ++r) s[r] = 0.f;
        #pragma unroll
        for (int tq = 0; tq < 4; ++tq)
            s = __builtin_amdgcn_mfma_f32_32x32x16_f16(kf[tq], qf[tq], s, 0, 0, 0);

        // ---- mask + exp2 + denominator (per-lane: q = lq) ----
        const int jb = kt * 32 + 4 * hi;
        float pe[16];
        #pragma unroll
        for (int r = 0; r < 16; ++r) {
            int j = jb + (r & 3) + ((r >> 2) << 3);      // D-row -> local key index
            float e = fexp2(s[r]);
            e = ((unsigned)(j - lo) <= span) ? e : 0.f;
            dsum += e;
            pe[r] = e;
        }
        // ---- P fragments: pack to f16 pairs, exchange across lane halves -> A-operand ----
        int d0 = packh2(pe[0],  pe[1]),  d1 = packh2(pe[2],  pe[3]);
        int d2 = packh2(pe[4],  pe[5]),  d3 = packh2(pe[6],  pe[7]);
        int d4 = packh2(pe[8],  pe[9]),  d5 = packh2(pe[10], pe[11]);
        int d6 = packh2(pe[12], pe[13]), d7 = packh2(pe[14], pe[15]);
        swap_halves(d0, d2, hi); swap_halves(d1, d3, hi);
        swap_halves(d4, d6, hi); swap_halves(d5, d7, hi);
        f16x8 pa0 = __builtin_bit_cast(f16x8, (int4v){d0, d1, d2, d3});   // keys kt*32 + 0..15
        f16x8 pa1 = __builtin_bit_cast(f16x8, (int4v){d4, d5, d6, d7});   // keys kt*32 + 16..31

        // ---- PV: O[32q][64h] += P . V ----
        o0 = __builtin_amdgcn_mfma_f32_32x32x16_f16(pa0, vb00, o0, 0, 0, 0);
        o0 = __builtin_amdgcn_mfma_f32_32x32x16_f16(pa1, vb01, o0, 0, 0, 0);
        o1 = __builtin_amdgcn_mfma_f32_32x32x16_f16(pa0, vb10, o1, 0, 0, 0);
        o1 = __builtin_amdgcn_mfma_f32_32x32x16_f16(pa1, vb11, o1, 0, 0, 0);

        __syncthreads();   // barrier 1: all waves' reads of slot (i&3) complete

        if (i < 4) {
            const int T = i + 4, ws = T & 3;   // == i&3, the slot just freed
            *(f16x4*)(smem + kaddr(ws, rK,      h4 << 1)) = (f16x4){(f16)gk0.x, (f16)gk0.y, (f16)gk0.z, (f16)gk0.w};
            *(f16x4*)(smem + kaddr(ws, rK + 16, h4 << 1)) = (f16x4){(f16)gk1.x, (f16)gk1.y, (f16)gk1.z, (f16)gk1.w};
            int vcbw = ws * 64 + rV0 * 2;
            *(f16x2*)(smem + vaddr(h4 + 0, vcbw)) = (f16x2){(f16)gv0.x, (f16)gv1.x};
            *(f16x2*)(smem + vaddr(h4 + 1, vcbw)) = (f16x2){(f16)gv0.y, (f16)gv1.y};
            *(f16x2*)(smem + vaddr(h4 + 2, vcbw)) = (f16x2){(f16)gv0.z, (f16)gv1.z};
            *(f16x2*)(smem + vaddr(h4 + 3, vcbw)) = (f16x2){(f16)gv0.w, (f16)gv1.w};
            __syncthreads();   // barrier 2: new tile visible for next iteration
        }
    }

    // ---- denominators: full per-query sum, reciprocal, per-row redistribute ----
    float dtot = dsum + __shfl_xor(dsum, 32, 64);
    float dinv = 1.0f / dtot;

    // last iteration's barrier 1 already passed; LDS free for O staging
    #pragma unroll
    for (int r = 0; r < 16; ++r) {
        int qloc = (r & 3) + ((r >> 2) << 3) + 4 * hi;
        float rd = __shfl(dinv, qloc, 64);     // dinv of query qloc lives in lane qloc
        int row = wq * 32 + qloc;
        O_lds[oaddr(row, lq)]      = o0[r] * rd;
        O_lds[oaddr(row, 32 + lq)] = o1[r] * rd;
    }
    __syncthreads();

    // coalesced float4 stores: out[b][c*128+row][n][h]
    const size_t ob = ((size_t)b * L + (size_t)c * CQ) * RS + (size_t)n * H;
    #pragma unroll
    for (int it = 0; it < 8; ++it) {
        int flat = it * 256 + t;
        int row  = flat >> 4;
        int hh   = (flat & 15) << 2;
        float4 val = *(const float4*)(O_lds + oaddr(row, hh));
        *(float4*)(o_ + ob + (size_t)row * RS + hh) = val;
    }
}

extern "C" void kernel_launch(void* const* d_in, const int* in_sizes, int n_in,
                              void* d_out, int out_size, void* d_ws, size_t ws_size,
                              hipStream_t stream) {
    const float* q = (const float*)d_in[0];
    const float* k = (const float*)d_in[1];
    const float* v = (const float*)d_in[2];
    float* o = (float*)d_out;
    (void)in_sizes; (void)n_in; (void)out_size; (void)d_ws; (void)ws_size;
    wattn_kernel<<<dim3(NB * NH * NC), dim3(256), 0, stream>>>(q, k, v, o);
}

// Round 6
// 49.919 us; speedup vs baseline: 2.8265x; 2.8265x over previous
//
#include <hip/hip_runtime.h>

// Sliding-window attention, window=127 (+-63), B=4 L=4096 NH=16 H=64, fp32 in/out.
// Round-6: R4 structure (monolithic stage->barrier->compute, best so far 54us) with 2x
// wave concurrency via key-split wave pairs.
//  - FROZEN RULE (R3+R5 evidence): no register prefetch across MFMA, no sched_barrier
//    pinning -> both rounds produced 64-VGPR spill pathology (WRITE_SIZE 3-4x).
//  - 512 threads = 8 waves; query tile qt owned by wave pair (qt: kt=qt..qt+2,
//    qt+4: kt=qt+3..qt+4); partials (o, denom) combined through LDS at the end.
//  - LDS 80KB = Q 16K + K 32K + V 32K -> 2 blocks/CU, 16 waves/CU (occ 19% -> ~50%).
//  - All layouts/swizzles identical to R4 (proven: conflicts 2M, clean 64MB writes).

typedef _Float16 f16;
typedef _Float16 f16x2  __attribute__((ext_vector_type(2)));
typedef _Float16 f16x4  __attribute__((ext_vector_type(4)));
typedef _Float16 f16x8  __attribute__((ext_vector_type(8)));
typedef float    f32x16 __attribute__((ext_vector_type(16)));
typedef int      int4v  __attribute__((ext_vector_type(4)));

constexpr int NB = 4, L = 4096, NH = 16, H = 64;
constexpr int CQ = 128, NC = L / CQ, KW = 256, WR = 63;
constexpr int RS = NH * H;   // seq-row stride in floats

constexpr int Q_OFF = 0;         // [128][64] f16, 128B rows, swizzled (16 KB)
constexpr int K_OFF = 16384;     // [256][64] f16, 128B rows, swizzled (32 KB)
constexpr int V_OFF = 49152;     // [64][256] f16 transposed, 512B rows, swizzled (32 KB)
constexpr int LDS_BYTES = 81920; // 80 KiB -> exactly 2 blocks/CU

#define DEV static __device__ __forceinline__

DEV int iclamp(int x, int lo, int hi) { return x < lo ? lo : (x > hi ? hi : x); }

DEV float fexp2(float x) {
#if __has_builtin(__builtin_amdgcn_exp2f)
    return __builtin_amdgcn_exp2f(x);
#else
    return exp2f(x);
#endif
}

DEV int packh2(float a, float b) {
    f16x2 p; p.x = (f16)a; p.y = (f16)b;   // RNE casts
    return __builtin_bit_cast(int, p);
}

// byte offset in row-major [R][64] f16 tile (128B rows), bank-conflict swizzle
DEV int rmaddr(int base, int r, int colb) {
    return base + r * 128 + (colb ^ ((r & 7) << 4));
}

// byte offset of (row h, key byte kb) in transposed V_lds (512B rows)
DEV int vaddr(int h, int kb) {
    return V_OFF + ((h * 512 + kb) ^ ((((h & 7) ^ ((h >> 3) & 7))) << 4));
}

// float index of (row q, col h) in swizzled O_lds
DEV int oaddr(int row, int col) {
    return (row * 64 + col) ^ ((row & 3) << 2);
}

// After call: new_a[l<32]=a[l], new_a[l>=32]=b[l^32]; new_b[l<32]=a[l^32], new_b[l>=32]=b[l].
DEV void swap_halves(int& a, int& b, int hi) {
    int pa = __shfl_xor(a, 32, 64);
    int pb = __shfl_xor(b, 32, 64);
    int na = hi ? pb : a;
    int nb = hi ? b  : pa;
    a = na; b = nb;
}

__global__ __launch_bounds__(512, 4)
void wattn_kernel(const float* __restrict__ q_, const float* __restrict__ k_,
                  const float* __restrict__ v_, float* __restrict__ o_)
{
    __shared__ alignas(16) char smem[LDS_BYTES];
    float* O_lds = (float*)smem;              // aliases Q + half of K after post-loop barrier
    float* D_lds = (float*)(smem + 32768);    // 128 partial denominators (in old K region)

    // XCD-aware swizzle: 2048 blocks, 8 XCDs, 2048%8==0 -> bijective
    const int bid = (int)blockIdx.x;
    const int wid = (bid & 7) * ((NB * NH * NC) / 8) + (bid >> 3);
    const int c = wid & (NC - 1);
    const int n = (wid >> 5) & (NH - 1);
    const int b = wid >> 9;

    const int t    = (int)threadIdx.x;
    const int lane = t & 63;
    const int w    = t >> 6;        // wave 0..7
    const int lq   = lane & 31;
    const int hi   = lane >> 5;
    const int qt   = w & 3;         // query tile 0..3
    const int half = w >> 2;        // 0: key tiles qt..qt+2, 1: qt+3..qt+4

    const int kg0 = c * CQ - WR;                       // global seq row of window key j=0
    const size_t bn = ((size_t)b * L * NH + n) * H;    // element offset of (b,0,n,0)
    const float qs = 0.125f * 1.44269504088896f;       // h^-0.5 * log2(e)

    // staging thread->element mapping: 32 threads per 256B source row region
    const int h4 = (t & 15) << 2;    // float col 0,4,..,60
    const int cb = h4 << 1;          // f16 byte col
    const int ru = t >> 4;           // 0..31

    // ---- Q stage (scaled f16), rows 0..127 ----
    {
        const float* qp = q_ + bn + (size_t)(c * CQ) * RS + h4;
        #pragma unroll
        for (int p = 0; p < 4; ++p) {
            int r = ru + p * 32;
            float4 x = *(const float4*)(qp + (size_t)r * RS);
            *(f16x4*)(smem + rmaddr(Q_OFF, r, cb)) =
                (f16x4){(f16)(x.x * qs), (f16)(x.y * qs), (f16)(x.z * qs), (f16)(x.w * qs)};
        }
    }
    // ---- K stage, rows 0..255 (edge-clamped; masked in softmax) ----
    #pragma unroll
    for (int p = 0; p < 8; ++p) {
        int r  = ru + p * 32;
        int kr = iclamp(kg0 + r, 0, L - 1);
        float4 x = *(const float4*)(k_ + bn + (size_t)kr * RS + h4);
        *(f16x4*)(smem + rmaddr(K_OFF, r, cb)) =
            (f16x4){(f16)x.x, (f16)x.y, (f16)x.z, (f16)x.w};
    }
    // ---- V stage transposed [64h][256k] ----
    #pragma unroll
    for (int p = 0; p < 4; ++p) {
        int r0  = ru * 2 + p * 64;
        int kr0 = iclamp(kg0 + r0,     0, L - 1);
        int kr1 = iclamp(kg0 + r0 + 1, 0, L - 1);
        float4 v0 = *(const float4*)(v_ + bn + (size_t)kr0 * RS + h4);
        float4 v1 = *(const float4*)(v_ + bn + (size_t)kr1 * RS + h4);
        int kb = r0 * 2;
        *(f16x2*)(smem + vaddr(h4 + 0, kb)) = (f16x2){(f16)v0.x, (f16)v1.x};
        *(f16x2*)(smem + vaddr(h4 + 1, kb)) = (f16x2){(f16)v0.y, (f16)v1.y};
        *(f16x2*)(smem + vaddr(h4 + 2, kb)) = (f16x2){(f16)v0.z, (f16)v1.z};
        *(f16x2*)(smem + vaddr(h4 + 3, kb)) = (f16x2){(f16)v0.w, (f16)v1.w};
    }

    // window mask bounds: allowed local keys j with j-iq in [0,126] and kg0+j in [0,L)
    const int iq  = qt * 32 + lq;
    const int jlo = (c == 0) ? WR : 0;
    const int jhi = (KW < L - kg0) ? KW : (L - kg0);
    const int lo  = (iq > jlo) ? iq : jlo;
    const int hb  = (iq + 126 < jhi - 1) ? (iq + 126) : (jhi - 1);
    const unsigned span = (unsigned)(hb - lo);

    f32x16 o0, o1;
    #pragma unroll
    for (int r = 0; r < 16; ++r) { o0[r] = 0.f; o1[r] = 0.f; }
    float dsum = 0.f;

    __syncthreads();   // staging complete

    // ---- Q fragments from LDS (B-operand: lane holds Q[q=lq][h=16tq+8hi+j]) ----
    f16x8 qf[4];
    #pragma unroll
    for (int tq = 0; tq < 4; ++tq)
        qf[tq] = *(const f16x8*)(smem + rmaddr(Q_OFF, qt * 32 + lq, 32 * tq + 16 * hi));

    auto body = [&](int kt) {
        // K fragments (A-operand: lane holds K[k=kt*32+lq][h=16tq+8hi+j])
        f16x8 kf[4];
        #pragma unroll
        for (int tq = 0; tq < 4; ++tq)
            kf[tq] = *(const f16x8*)(smem + rmaddr(K_OFF, kt * 32 + lq, 32 * tq + 16 * hi));

        // S^T tile = K_tile(32k x 64h) . Q^T
        f32x16 s;
        #pragma unroll
        for (int r = 0; r < 16; ++r) s[r] = 0.f;
        #pragma unroll
        for (int tq = 0; tq < 4; ++tq)
            s = __builtin_amdgcn_mfma_f32_32x32x16_f16(kf[tq], qf[tq], s, 0, 0, 0);

        // mask + exp2 + denominator (per-lane: q = lq)
        const int jb = kt * 32 + 4 * hi;
        float pe[16];
        #pragma unroll
        for (int r = 0; r < 16; ++r) {
            int j = jb + (r & 3) + ((r >> 2) << 3);      // D-row -> local key index
            float e = fexp2(s[r]);
            e = ((unsigned)(j - lo) <= span) ? e : 0.f;
            dsum += e;
            pe[r] = e;
        }
        // P fragments: pack to f16 pairs, exchange across lane halves -> A-operand
        int d0 = packh2(pe[0],  pe[1]),  d1 = packh2(pe[2],  pe[3]);
        int d2 = packh2(pe[4],  pe[5]),  d3 = packh2(pe[6],  pe[7]);
        int d4 = packh2(pe[8],  pe[9]),  d5 = packh2(pe[10], pe[11]);
        int d6 = packh2(pe[12], pe[13]), d7 = packh2(pe[14], pe[15]);
        swap_halves(d0, d2, hi); swap_halves(d1, d3, hi);
        swap_halves(d4, d6, hi); swap_halves(d5, d7, hi);
        f16x8 pa0 = __builtin_bit_cast(f16x8, (int4v){d0, d1, d2, d3});   // keys kt*32 + 0..15
        f16x8 pa1 = __builtin_bit_cast(f16x8, (int4v){d4, d5, d6, d7});   // keys kt*32 + 16..31

        // PV: O[32q][64h] += P . V (B-operand from swizzled transposed V)
        const int kb = kt * 64 + hi * 16;
        f16x8 vb00 = *(const f16x8*)(smem + vaddr(lq,      kb));
        f16x8 vb01 = *(const f16x8*)(smem + vaddr(lq,      kb + 32));
        f16x8 vb10 = *(const f16x8*)(smem + vaddr(32 + lq, kb));
        f16x8 vb11 = *(const f16x8*)(smem + vaddr(32 + lq, kb + 32));
        o0 = __builtin_amdgcn_mfma_f32_32x32x16_f16(pa0, vb00, o0, 0, 0, 0);
        o0 = __builtin_amdgcn_mfma_f32_32x32x16_f16(pa1, vb01, o0, 0, 0, 0);
        o1 = __builtin_amdgcn_mfma_f32_32x32x16_f16(pa0, vb10, o1, 0, 0, 0);
        o1 = __builtin_amdgcn_mfma_f32_32x32x16_f16(pa1, vb11, o1, 0, 0, 0);
    };

    // key-split: low wave 3 tiles, high wave 2 tiles (union = qt..qt+4)
    const int kt0 = qt + half * 3;
    body(kt0);
    body(kt0 + 1);
    if (!half) body(kt0 + 2);

    // per-query partial denominator within this wave
    float dw = dsum + __shfl_xor(dsum, 32, 64);

    __syncthreads();   // all waves done reading Q/K/V LDS; reuse for partials

    if (half) {
        // high wave: publish unnormalized partial O and partial denom
        #pragma unroll
        for (int r = 0; r < 16; ++r) {
            int qloc = (r & 3) + ((r >> 2) << 3) + 4 * hi;
            int row  = qt * 32 + qloc;
            O_lds[oaddr(row, lq)]      = o0[r];
            O_lds[oaddr(row, 32 + lq)] = o1[r];
        }
        if (lane < 32) D_lds[qt * 32 + lq] = dw;
    }
    __syncthreads();

    if (!half) {
        // low wave: combine, normalize, write final O into same slots
        float dinv = 1.0f / (dw + D_lds[iq]);
        #pragma unroll
        for (int r = 0; r < 16; ++r) {
            int qloc = (r & 3) + ((r >> 2) << 3) + 4 * hi;
            int row  = qt * 32 + qloc;
            float rd = __shfl(dinv, qloc, 64);   // dinv of query qloc lives in lane qloc
            int a0 = oaddr(row, lq), a1 = oaddr(row, 32 + lq);
            O_lds[a0] = (o0[r] + O_lds[a0]) * rd;
            O_lds[a1] = (o1[r] + O_lds[a1]) * rd;
        }
    }
    __syncthreads();

    // coalesced float4 stores: out[b][c*128+row][n][h]  (4 iters over 512 threads)
    const size_t ob = ((size_t)b * L + (size_t)c * CQ) * RS + (size_t)n * H;
    #pragma unroll
    for (int it = 0; it < 4; ++it) {
        int flat = it * 512 + t;
        int row  = flat >> 4;
        int hh   = (flat & 15) << 2;
        float4 val = *(const float4*)(O_lds + oaddr(row, hh));
        *(float4*)(o_ + ob + (size_t)row * RS + hh) = val;
    }
}

extern "C" void kernel_launch(void* const* d_in, const int* in_sizes, int n_in,
                              void* d_out, int out_size, void* d_ws, size_t ws_size,
                              hipStream_t stream) {
    const float* q = (const float*)d_in[0];
    const float* k = (const float*)d_in[1];
    const float* v = (const float*)d_in[2];
    float* o = (float*)d_out;
    (void)in_sizes; (void)n_in; (void)out_size; (void)d_ws; (void)ws_size;
    wattn_kernel<<<dim3(NB * NH * NC), dim3(512), 0, stream>>>(q, k, v, o);
}